// Round 5
// baseline (405.418 us; speedup 1.0000x reference)
//
#include <hip/hip_runtime.h>
#include <hip/hip_bf16.h>

typedef __bf16 bf16;
typedef __attribute__((ext_vector_type(8))) __bf16 bf16x8;
typedef __attribute__((ext_vector_type(4))) float f32x4;

#define GLDS16(gp, lp) __builtin_amdgcn_global_load_lds( \
    (const __attribute__((address_space(1))) void*)(gp),  \
    (__attribute__((address_space(3))) void*)(lp), 16, 0, 0)

// ---------------------------------------------------------------------------
// Generic bf16 MFMA GEMM:  C[i][j] = sum_k A[i][k] * Bt[j][k]   (Bt = B^T)
// Tile 128 x BN (BN in {64,128,256}), BK=32, 512 threads = 8 waves (2x4).
// Per wave: 64 rows x (BN/4) cols -> 4 x (BN/64) fragments of 16x16.
// Double-buffered LDS, 2-phase pipeline (stage t+1 before compute t, one
// barrier per K-step). blockIdx.y = batch ((bb<<3)|bh strides);
// blockIdx.z = K-split (chunk KC, output offset z*zC).
// EPI: 0 = store bf16; 1 = store f32*scale (+zC partial offset);
//      3 = f32 atomicAdd (split-K accumulate);
//      4 = fused row-softmax epilogue -> store P bf16 (BN==256 only).
// ---------------------------------------------------------------------------
template<int EPI, int BN>
__global__ __launch_bounds__(512)
void gemm_bt(const bf16* __restrict__ A, int lda, long sAb, long sAh,
             const bf16* __restrict__ Bt, int ldb, long sBb, long sBh,
             void* __restrict__ Cp, int ldc, long sCb, long sCh, long zC,
             int KC, int tilesN, float scale)
{
    constexpr int CT = BN / 64;      // col frags per wave
    constexpr int CW = 16 * CT;      // cols per wave

    __shared__ __align__(16) bf16 Al[2][128 * 32];
    __shared__ __align__(16) bf16 Bl[2][BN * 32];
    __shared__ float red[1024];      // softmax cross-wave reduce (EPI==4)

    const int t    = threadIdx.x;
    const int lane = t & 63;
    const int w    = t >> 6;
    const int wr   = w >> 2, wc = w & 3;
    const int tm = blockIdx.x / tilesN, tn = blockIdx.x % tilesN;
    const int row0 = tm * 128, col0 = tn * BN;
    const int bb = blockIdx.y >> 3, bh = blockIdx.y & 7;
    const int koff = blockIdx.z * KC;

    const bf16* Ab = A  + (long)bb * sAb + (long)bh * sAh;
    const bf16* Bb = Bt + (long)bb * sBb + (long)bh * sBh;

    // staging: chunk q -> row q>>2, col (q&3)*8 ; thread t handles q = t (+512)
    const int sr = t >> 2;
    const int sc = (t & 3) * 8;
    const long aoff  = (long)(row0 + sr) * lda + koff + sc;
    const long boff0 = (long)(col0 + sr) * ldb + koff + sc;
    const long boff1 = (long)(col0 + 128 + sr) * ldb + koff + sc;  // BN==256 only

    f32x4 acc[4][CT];
#pragma unroll
    for (int i = 0; i < 4; i++)
#pragma unroll
        for (int j = 0; j < CT; j++) acc[i][j] = (f32x4){0.f, 0.f, 0.f, 0.f};

    const int fr = lane & 15, hi = lane >> 4;
    const int nt = KC >> 5;
    int cur = 0;

    auto STAGE = [&](int buf, int kk) {
        GLDS16(Ab + aoff + kk, &Al[buf][w * 512]);
        if constexpr (BN >= 128) {
            GLDS16(Bb + boff0 + kk, &Bl[buf][w * 512]);
            if constexpr (BN == 256)
                GLDS16(Bb + boff1 + kk, &Bl[buf][4096 + w * 512]);
        } else {
            if (w < 4) GLDS16(Bb + boff0 + kk, &Bl[buf][w * 512]);
        }
    };

    STAGE(0, 0);
    __syncthreads();

    for (int tt = 0; tt < nt; ++tt) {
        if (tt + 1 < nt) STAGE(cur ^ 1, (tt + 1) * 32);
        bf16x8 af[4], bfr[CT];
#pragma unroll
        for (int rt = 0; rt < 4; rt++)
            af[rt] = *(const bf16x8*)&Al[cur][(wr * 64 + rt * 16 + fr) * 32 + hi * 8];
#pragma unroll
        for (int ct = 0; ct < CT; ct++)
            bfr[ct] = *(const bf16x8*)&Bl[cur][(wc * CW + ct * 16 + fr) * 32 + hi * 8];
#pragma unroll
        for (int rt = 0; rt < 4; rt++)
#pragma unroll
            for (int ct = 0; ct < CT; ct++)
                acc[rt][ct] = __builtin_amdgcn_mfma_f32_16x16x32_bf16(
                    af[rt], bfr[ct], acc[rt][ct], 0, 0, 0);
        __syncthreads();   // drains vmcnt(0)+lgkmcnt(0): stage(t+1) complete
        cur ^= 1;
    }

    const long cbase = (long)bb * sCb + (long)bh * sCh + (long)blockIdx.z * zC;

    if constexpr (EPI == 4) {
        // ---- fused row softmax over BN=256 cols (full key range in block) ----
#pragma unroll
        for (int rt = 0; rt < 4; rt++)
#pragma unroll
            for (int ct = 0; ct < CT; ct++) acc[rt][ct] *= scale;

        float m[4][4];
#pragma unroll
        for (int rt = 0; rt < 4; rt++)
#pragma unroll
            for (int j = 0; j < 4; j++) {
                float mm = acc[rt][0][j];
#pragma unroll
                for (int ct = 1; ct < CT; ct++) mm = fmaxf(mm, acc[rt][ct][j]);
#pragma unroll
                for (int off = 1; off < 16; off <<= 1)
                    mm = fmaxf(mm, __shfl_xor(mm, off));
                m[rt][j] = mm;
            }
        if (fr == 0) {
#pragma unroll
            for (int rt = 0; rt < 4; rt++)
#pragma unroll
                for (int j = 0; j < 4; j++)
                    red[wc * 128 + wr * 64 + rt * 16 + hi * 4 + j] = m[rt][j];
        }
        __syncthreads();
#pragma unroll
        for (int rt = 0; rt < 4; rt++)
#pragma unroll
            for (int j = 0; j < 4; j++) {
                const int rl = wr * 64 + rt * 16 + hi * 4 + j;
                m[rt][j] = fmaxf(fmaxf(red[rl], red[128 + rl]),
                                 fmaxf(red[256 + rl], red[384 + rl]));
            }
        float ss[4][4];
#pragma unroll
        for (int rt = 0; rt < 4; rt++)
#pragma unroll
            for (int j = 0; j < 4; j++) ss[rt][j] = 0.f;
#pragma unroll
        for (int rt = 0; rt < 4; rt++)
#pragma unroll
            for (int ct = 0; ct < CT; ct++)
#pragma unroll
                for (int j = 0; j < 4; j++) {
                    const float e = __expf(acc[rt][ct][j] - m[rt][j]);
                    acc[rt][ct][j] = e;
                    ss[rt][j] += e;
                }
#pragma unroll
        for (int rt = 0; rt < 4; rt++)
#pragma unroll
            for (int j = 0; j < 4; j++) {
#pragma unroll
                for (int off = 1; off < 16; off <<= 1)
                    ss[rt][j] += __shfl_xor(ss[rt][j], off);
            }
        if (fr == 0) {
#pragma unroll
            for (int rt = 0; rt < 4; rt++)
#pragma unroll
                for (int j = 0; j < 4; j++)
                    red[512 + wc * 128 + wr * 64 + rt * 16 + hi * 4 + j] = ss[rt][j];
        }
        __syncthreads();
#pragma unroll
        for (int rt = 0; rt < 4; rt++)
#pragma unroll
            for (int j = 0; j < 4; j++) {
                const int rl = wr * 64 + rt * 16 + hi * 4 + j;
                m[rt][j] = 1.f / (red[512 + rl] + red[640 + rl] +
                                  red[768 + rl] + red[896 + rl]);
            }
        bf16* P = (bf16*)Cp;
#pragma unroll
        for (int rt = 0; rt < 4; rt++)
#pragma unroll
            for (int j = 0; j < 4; j++) {
                const int row = row0 + wr * 64 + rt * 16 + hi * 4 + j;
#pragma unroll
                for (int ct = 0; ct < CT; ct++) {
                    const int col = col0 + wc * CW + ct * 16 + fr;
                    P[cbase + (long)row * ldc + col] = (bf16)(acc[rt][ct][j] * m[rt][j]);
                }
            }
        return;
    }

#pragma unroll
    for (int rt = 0; rt < 4; rt++) {
#pragma unroll
        for (int j = 0; j < 4; j++) {
            const int row = row0 + wr * 64 + rt * 16 + hi * 4 + j;
#pragma unroll
            for (int ct = 0; ct < CT; ct++) {
                const int col = col0 + wc * CW + ct * 16 + fr;
                const float v = acc[rt][ct][j];
                const long idx = cbase + (long)row * ldc + col;
                if constexpr (EPI == 0) {
                    ((bf16*)Cp)[idx] = (bf16)v;
                } else if constexpr (EPI == 1) {
                    ((float*)Cp)[idx] = v * scale;
                } else {
                    atomicAdd(((float*)Cp) + idx, v);
                }
            }
        }
    }
}

// ---------------------------------------------------------------------------
// Elementwise f32 -> bf16 (4 per thread)
// ---------------------------------------------------------------------------
__global__ void cvt_f32_bf16(const float* __restrict__ in, bf16* __restrict__ out, int n4)
{
    const int i = blockIdx.x * 256 + threadIdx.x;
    if (i < n4) {
        const float4 v = *(const float4*)&in[(long)i * 4];
        union { bf16 h[4]; ushort4 u; } o;
        o.h[0] = (bf16)v.x; o.h[1] = (bf16)v.y; o.h[2] = (bf16)v.z; o.h[3] = (bf16)v.w;
        *(ushort4*)&out[(long)i * 4] = o.u;
    }
}

// ---------------------------------------------------------------------------
// Transpose + cvt for 512x512 fp32 weight matrices (W[c][j] -> Wt[j][c] bf16)
// ---------------------------------------------------------------------------
__global__ __launch_bounds__(256)
void wtrans(const float* __restrict__ Wq, const float* __restrict__ Wk,
            const float* __restrict__ Wv, const float* __restrict__ Wo,
            bf16* __restrict__ wqkv_t, bf16* __restrict__ wo_t)
{
    __shared__ __align__(16) float T[64][68];
    const int z = blockIdx.z;
    const float* src = (z == 0) ? Wq : (z == 1) ? Wk : (z == 2) ? Wv : Wo;
    bf16* dst = (z < 3) ? (wqkv_t + (long)z * 262144) : wo_t;
    const int r0 = blockIdx.x * 64, c0 = blockIdx.y * 64;
    const int t  = threadIdx.x;
    const int rl = t >> 2;
    const int cq = (t & 3) * 16;
#pragma unroll
    for (int i = 0; i < 4; i++) {
        const float4 v = *(const float4*)&src[(long)(r0 + rl) * 512 + c0 + cq + i * 4];
        T[cq + i * 4 + 0][rl] = v.x;
        T[cq + i * 4 + 1][rl] = v.y;
        T[cq + i * 4 + 2][rl] = v.z;
        T[cq + i * 4 + 3][rl] = v.w;
    }
    __syncthreads();
#pragma unroll
    for (int i = 0; i < 4; i++) {
        const float4 v = *(const float4*)&T[rl][cq + i * 4];
        union { bf16 h[4]; ushort4 u; } o;
        o.h[0] = (bf16)v.x; o.h[1] = (bf16)v.y; o.h[2] = (bf16)v.z; o.h[3] = (bf16)v.w;
        *(ushort4*)&dst[(long)(c0 + rl) * 512 + r0 + cq + i * 4] = o.u;
    }
}

// ---------------------------------------------------------------------------
// Transpose V region of qkv (bf16): vt[b*512 + (j-1024)][l] = qkv[b*256+l][j]
// ---------------------------------------------------------------------------
__global__ __launch_bounds__(256)
void vtrans(const bf16* __restrict__ qkv, bf16* __restrict__ vt)
{
    __shared__ __align__(16) bf16 T[64][72];
    const int t  = threadIdx.x;
    const int l0 = blockIdx.x * 64, j0 = blockIdx.y * 64, b = blockIdx.z;
    const int r  = t >> 3;
    const int c8 = (t & 7) * 8;
#pragma unroll
    for (int p = 0; p < 2; p++) {
        const int rr = r + p * 32;
        bf16 v[8];
        *(uint4*)v = *(const uint4*)&qkv[(long)(b * 256 + l0 + rr) * 1536 + 1024 + j0 + c8];
#pragma unroll
        for (int i = 0; i < 8; i++) T[c8 + i][rr] = v[i];
    }
    __syncthreads();
#pragma unroll
    for (int p = 0; p < 2; p++) {
        const int rr = r + p * 32;
        const uint4 val = *(const uint4*)&T[rr][c8];
        *(uint4*)&vt[(long)(b * 512 + j0 + rr) * 256 + l0 + c8] = val;
    }
}

// ---------------------------------------------------------------------------
// im2col scatter helper: pooled value (b,lp,c) -> 3 ic slots + boundary zeros
// ic layout: [32*Ld][1536], entry (l, ci*3+t) = pooled[l+t-1] (0 if OOB)
// ---------------------------------------------------------------------------
__device__ inline void ic_scatter(bf16* __restrict__ icb, int lp, int Ld, float pooled)
{
    const bf16 pb = (bf16)pooled;
    icb[(long)lp * 1536 + 1] = pb;
    if (lp + 1 < Ld) icb[(long)(lp + 1) * 1536] = pb;
    if (lp > 0)      icb[(long)(lp - 1) * 1536 + 2] = pb;
    if (lp == 0)      icb[0] = (bf16)0.f;
    if (lp == Ld - 1) icb[(long)(Ld - 1) * 1536 + 2] = (bf16)0.f;
}

// ---------------------------------------------------------------------------
// Head of cascade: attn_out = features + wo_p0 + wo_p1 (Wo split-K partials);
// writes out & sf, pool(k=2), im2col, zero conv accumulator.
// One thread per pooled element (32*128*512 = 2M).
// ---------------------------------------------------------------------------
__global__ void cascade_first(const float* __restrict__ features,
                              const float* __restrict__ p0,
                              const float* __restrict__ p1,
                              float* __restrict__ out,
                              float* __restrict__ sf,
                              bf16* __restrict__ ic,
                              float* __restrict__ convz)
{
    const int idx = blockIdx.x * 256 + threadIdx.x;
    const int c  = idx & 511;
    const int lp = (idx >> 9) & 127;
    const int b  = idx >> 16;
    const long e0 = (long)(b * 256 + lp * 2) * 512 + c;
    const long e1 = e0 + 512;
    const float a0 = features[e0] + p0[e0] + p1[e0];
    const float a1 = features[e1] + p0[e1] + p1[e1];
    out[e0] = a0; out[e1] = a1;
    sf[e0]  = a0; sf[e1]  = a1;
    convz[idx] = 0.f;
    ic_scatter(ic + (long)b * 128 * 1536 + (long)c * 3, lp, 128, (a0 + a1) * 0.5f);
}

// ---------------------------------------------------------------------------
// depth d>=1: upsample(conv_{d-1})+bias+relu -> sf writeback -> pool(k) ->
// im2col -> zero conv accumulator. One thread per pooled element (32*Ld*512).
// ---------------------------------------------------------------------------
__global__ void cascade_mid(const float* __restrict__ conv,
                            const float* __restrict__ bias_p,
                            float* __restrict__ sf,
                            bf16* __restrict__ ic,
                            float* __restrict__ convz,
                            int ldshift, int k, float invk, float scale)
{
    const int idx = blockIdx.x * 256 + threadIdx.x;
    const int Ld = 1 << ldshift;
    const int c  = idx & 511;
    const int lp = (idx >> 9) & (Ld - 1);
    const int b  = idx >> (9 + ldshift);
    const int Lprev = Ld << 1;
    const float bias = bias_p[c];
    float* sfp = sf + ((long)b * 256 + (long)lp * k) * 512 + c;
    const float* cvb = conv + (long)b * Lprev * 512 + c;
    float s = 0.f;
    for (int i = 0; i < k; i++) {
        const int j = lp * k + i;
        float coords = (j + 0.5f) * scale - 0.5f;
        coords = fminf(fmaxf(coords, 0.f), (float)(Lprev - 1));
        const int lo = (int)coords;
        const int hi2 = min(lo + 1, Lprev - 1);
        const float w = coords - (float)lo;
        const float vlo = fmaxf(cvb[(long)lo * 512] + bias, 0.f);
        const float vhi = fmaxf(cvb[(long)hi2 * 512] + bias, 0.f);
        const float v = sfp[(long)i * 512] + vlo * (1.f - w) + vhi * w;
        sfp[(long)i * 512] = v;
        s += v;
    }
    convz[idx] = 0.f;
    ic_scatter(ic + (long)b * Ld * 1536 + (long)c * 3, lp, Ld, s * invk);
}

// ---------------------------------------------------------------------------
// final: out = attn_out + sf + upsample(relu(conv5 + bias))
// ---------------------------------------------------------------------------
__global__ void upsample_final(const float* __restrict__ conv,
                               const float* __restrict__ bias_p,
                               const float* __restrict__ sf,
                               float* __restrict__ outp)
{
    const int idx = blockIdx.x * 256 + threadIdx.x;
    const int c = idx & 511;
    const int j = (idx >> 9) & 255;
    const int b = idx >> 17;
    const float bias = bias_p[c];
    float coords = (j + 0.5f) * (4.f / 256.f) - 0.5f;
    coords = fminf(fmaxf(coords, 0.f), 3.f);
    const int lo = (int)coords;
    const int hi2 = min(lo + 1, 3);
    const float w = coords - (float)lo;
    const long rb = (long)b * 4 * 512 + c;
    const float vlo = fmaxf(conv[rb + (long)lo * 512] + bias, 0.f);
    const float vhi = fmaxf(conv[rb + (long)hi2 * 512] + bias, 0.f);
    outp[idx] = outp[idx] + sf[idx] + vlo * (1.f - w) + vhi * w;
}

// ---------------------------------------------------------------------------
// workspace layout (bytes)
// ---------------------------------------------------------------------------
static const long OFF_XB    = 0;          //  8,388,608  features bf16
static const long OFF_WQKV  = 8388608;    //  1,572,864  [1536][512] bf16
static const long OFF_WO    = 9961472;    //    524,288  [512][512] bf16
static const long OFF_WCONV = 10485760;   //  9,437,184  [6][512][1536] bf16
static const long OFF_QKV   = 19922944;   // 25,165,824  [8192][1536] bf16
static const long OFF_VT    = 45088768;   //  8,388,608  [32][512][256] bf16
static const long OFF_P     = 53477376;   // 33,554,432  [65536][256] bf16
static const long OFF_CTX   = 87031808;   //  8,388,608  [8192][512] bf16
static const long OFF_WPART = 95420416;   // 33,554,432  [2][8192][512] f32
static const long OFF_IC    = 128974848;  // 12,582,912  [4096][1536] bf16
static const long OFF_CONVA = 141557760;  //  8,388,608  f32
static const long OFF_CONVB = 149946368;  //  4,194,304  f32
static const long OFF_SF    = 154140672;  // 16,777,216  [8192][512] f32
// total: 170,917,888 bytes

extern "C" void kernel_launch(void* const* d_in, const int* in_sizes, int n_in,
                              void* d_out, int out_size, void* d_ws, size_t ws_size,
                              hipStream_t stream)
{
    const float* features = (const float*)d_in[0];
    const float* Wq = (const float*)d_in[1];
    const float* Wk = (const float*)d_in[2];
    const float* Wv = (const float*)d_in[3];
    const float* Wo = (const float*)d_in[4];
    const float* conv_w = (const float*)d_in[5];
    const float* conv_b = (const float*)d_in[6];
    float* out = (float*)d_out;

    char* ws = (char*)d_ws;
    bf16* xb     = (bf16*)(ws + OFF_XB);
    bf16* wqkv_t = (bf16*)(ws + OFF_WQKV);
    bf16* wo_t   = (bf16*)(ws + OFF_WO);
    bf16* wconv  = (bf16*)(ws + OFF_WCONV);
    bf16* qkv    = (bf16*)(ws + OFF_QKV);
    bf16* vt     = (bf16*)(ws + OFF_VT);
    bf16* P      = (bf16*)(ws + OFF_P);
    bf16* ctx    = (bf16*)(ws + OFF_CTX);
    float* wpart = (float*)(ws + OFF_WPART);
    bf16* ic     = (bf16*)(ws + OFF_IC);
    float* convA = (float*)(ws + OFF_CONVA);
    float* convB = (float*)(ws + OFF_CONVB);
    float* sf    = (float*)(ws + OFF_SF);
    float* convbuf[2] = {convA, convB};

    // --- input conversions ---
    cvt_f32_bf16<<<4096, 256, 0, stream>>>(features, xb, 1048576);
    cvt_f32_bf16<<<4608, 256, 0, stream>>>(conv_w, wconv, 1179648);
    wtrans<<<dim3(8, 8, 4), 256, 0, stream>>>(Wq, Wk, Wv, Wo, wqkv_t, wo_t);

    // --- fused QKV projection: qkv[8192][1536] ---
    gemm_bt<0, 128><<<dim3(768, 1, 1), 512, 0, stream>>>(
        xb, 512, 0, 0, wqkv_t, 512, 0, 0, qkv, 1536, 0, 0, 0,
        512, 12, 1.f);

    // --- V transpose for PV GEMM ---
    vtrans<<<dim3(4, 8, 32), 256, 0, stream>>>(qkv, vt);

    // --- scores + fused softmax -> P bf16, batched over 256 (b,h) ---
    gemm_bt<4, 256><<<dim3(2, 256, 1), 512, 0, stream>>>(
        qkv, 1536, 393216, 64,
        qkv + 512, 1536, 393216, 64,
        P, 256, 524288, 65536, 0,
        64, 1, 0.125f);

    // --- ctx = P @ V : Bt = V^T (vt) ---
    gemm_bt<0, 64><<<dim3(2, 256, 1), 512, 0, stream>>>(
        P, 256, 524288, 65536,
        vt, 256, 131072, 16384,
        ctx, 512, 131072, 64, 0,
        256, 1, 1.f);

    // --- Wo GEMM, split-K=2 into partial buffers ---
    gemm_bt<1, 128><<<dim3(256, 1, 2), 512, 0, stream>>>(
        ctx, 512, 0, 0, wo_t, 512, 0, 0,
        wpart, 512, 0, 0, 4194304,
        256, 4, 1.f);

    // --- ScaleFeatures cascade ---
    static const int SPL[6] = {4, 8, 16, 16, 16, 16};

    // d = 0 (also materializes attn_out into out & sf)
    cascade_first<<<8192, 256, 0, stream>>>(
        features, wpart, wpart + 4194304, out, sf, ic, convbuf[0]);
    gemm_bt<3, 128><<<dim3(128, 1, SPL[0]), 512, 0, stream>>>(
        ic, 1536, 0, 0, wconv, 1536, 0, 0,
        convbuf[0], 512, 0, 0, 0,
        1536 / SPL[0], 4, 1.f);

    // d = 1..5
    for (int d = 1; d < 6; d++) {
        const int ldshift = 7 - d;
        const int Ld = 1 << ldshift;
        const int k  = 2 << d;
        cascade_mid<<<64 * Ld, 256, 0, stream>>>(
            convbuf[(d - 1) & 1], conv_b + (d - 1) * 512, sf, ic, convbuf[d & 1],
            ldshift, k, 1.0f / (float)k, (float)(2 * Ld) / 256.f);
        gemm_bt<3, 128><<<dim3((Ld / 4) * 4, 1, SPL[d]), 512, 0, stream>>>(
            ic, 1536, 0, 0,
            wconv + (long)d * 786432, 1536, 0, 0,
            convbuf[d & 1], 512, 0, 0, 0,
            1536 / SPL[d], 4, 1.f);
    }

    // --- final: out = attn_out + sf + up(relu(conv5 + b5)) ---
    upsample_final<<<16384, 256, 0, stream>>>(
        convbuf[1], conv_b + 5 * 512, sf, out);
}

// Round 7
// 368.421 us; speedup vs baseline: 1.1004x; 1.1004x over previous
//
#include <hip/hip_runtime.h>
#include <hip/hip_bf16.h>

typedef __bf16 bf16;
typedef __attribute__((ext_vector_type(8))) __bf16 bf16x8;
typedef __attribute__((ext_vector_type(4))) float f32x4;

#define GLDS16(gp, lp) __builtin_amdgcn_global_load_lds( \
    (const __attribute__((address_space(1))) void*)(gp),  \
    (__attribute__((address_space(3))) void*)(lp), 16, 0, 0)

// ---------------------------------------------------------------------------
// Generic bf16 MFMA GEMM:  C[i][j] = sum_k A[i][k] * Bt[j][k]   (Bt = B^T)
// Tile 128 x BN (BN in {64,128,256}), BK=32, 512 threads = 8 waves (2x4).
// Double-buffered LDS, 2-phase pipeline. blockIdx.y = batch; blockIdx.z =
// K-split (chunk KC, output offset z*zC -> partial buffers, NO atomics).
// EPI: 0 = store bf16; 1 = store f32*scale (+z*zC partial offset);
//      4 = fused row-softmax epilogue -> store P bf16 (BN==256 only).
// ---------------------------------------------------------------------------
template<int EPI, int BN>
__global__ __launch_bounds__(512)
void gemm_bt(const bf16* __restrict__ A, int lda, long sAb, long sAh,
             const bf16* __restrict__ Bt, int ldb, long sBb, long sBh,
             void* __restrict__ Cp, int ldc, long sCb, long sCh, long zC,
             int KC, int tilesN, float scale)
{
    constexpr int CT = BN / 64;      // col frags per wave
    constexpr int CW = 16 * CT;      // cols per wave

    __shared__ __align__(16) bf16 Al[2][128 * 32];
    __shared__ __align__(16) bf16 Bl[2][BN * 32];
    __shared__ float red[1024];      // softmax cross-wave reduce (EPI==4)

    const int t    = threadIdx.x;
    const int lane = t & 63;
    const int w    = t >> 6;
    const int wr   = w >> 2, wc = w & 3;
    const int tm = blockIdx.x / tilesN, tn = blockIdx.x % tilesN;
    const int row0 = tm * 128, col0 = tn * BN;
    const int bb = blockIdx.y >> 3, bh = blockIdx.y & 7;
    const int koff = blockIdx.z * KC;

    const bf16* Ab = A  + (long)bb * sAb + (long)bh * sAh;
    const bf16* Bb = Bt + (long)bb * sBb + (long)bh * sBh;

    // staging: chunk q -> row q>>2, col (q&3)*8 ; thread t handles q = t (+512)
    const int sr = t >> 2;
    const int sc = (t & 3) * 8;
    const long aoff  = (long)(row0 + sr) * lda + koff + sc;
    const long boff0 = (long)(col0 + sr) * ldb + koff + sc;
    const long boff1 = (long)(col0 + 128 + sr) * ldb + koff + sc;  // BN==256 only

    f32x4 acc[4][CT];
#pragma unroll
    for (int i = 0; i < 4; i++)
#pragma unroll
        for (int j = 0; j < CT; j++) acc[i][j] = (f32x4){0.f, 0.f, 0.f, 0.f};

    const int fr = lane & 15, hi = lane >> 4;
    const int nt = KC >> 5;
    int cur = 0;

    auto STAGE = [&](int buf, int kk) {
        GLDS16(Ab + aoff + kk, &Al[buf][w * 512]);
        if constexpr (BN >= 128) {
            GLDS16(Bb + boff0 + kk, &Bl[buf][w * 512]);
            if constexpr (BN == 256)
                GLDS16(Bb + boff1 + kk, &Bl[buf][4096 + w * 512]);
        } else {
            if (w < 4) GLDS16(Bb + boff0 + kk, &Bl[buf][w * 512]);
        }
    };

    STAGE(0, 0);
    __syncthreads();

    for (int tt = 0; tt < nt; ++tt) {
        if (tt + 1 < nt) STAGE(cur ^ 1, (tt + 1) * 32);
        bf16x8 af[4], bfr[CT];
#pragma unroll
        for (int rt = 0; rt < 4; rt++)
            af[rt] = *(const bf16x8*)&Al[cur][(wr * 64 + rt * 16 + fr) * 32 + hi * 8];
#pragma unroll
        for (int ct = 0; ct < CT; ct++)
            bfr[ct] = *(const bf16x8*)&Bl[cur][(wc * CW + ct * 16 + fr) * 32 + hi * 8];
#pragma unroll
        for (int rt = 0; rt < 4; rt++)
#pragma unroll
            for (int ct = 0; ct < CT; ct++)
                acc[rt][ct] = __builtin_amdgcn_mfma_f32_16x16x32_bf16(
                    af[rt], bfr[ct], acc[rt][ct], 0, 0, 0);
        __syncthreads();   // drains vmcnt(0)+lgkmcnt(0): stage(t+1) complete
        cur ^= 1;
    }

    const long cbase = (long)bb * sCb + (long)bh * sCh + (long)blockIdx.z * zC;

    if constexpr (EPI == 4) {
        // ---- fused row softmax over BN=256 cols (full key range in block) ----
#pragma unroll
        for (int rt = 0; rt < 4; rt++)
#pragma unroll
            for (int ct = 0; ct < CT; ct++) acc[rt][ct] *= scale;

        float m[4][4];
#pragma unroll
        for (int rt = 0; rt < 4; rt++)
#pragma unroll
            for (int j = 0; j < 4; j++) {
                float mm = acc[rt][0][j];
#pragma unroll
                for (int ct = 1; ct < CT; ct++) mm = fmaxf(mm, acc[rt][ct][j]);
#pragma unroll
                for (int off = 1; off < 16; off <<= 1)
                    mm = fmaxf(mm, __shfl_xor(mm, off));
                m[rt][j] = mm;
            }
        if (fr == 0) {
#pragma unroll
            for (int rt = 0; rt < 4; rt++)
#pragma unroll
                for (int j = 0; j < 4; j++)
                    red[wc * 128 + wr * 64 + rt * 16 + hi * 4 + j] = m[rt][j];
        }
        __syncthreads();
#pragma unroll
        for (int rt = 0; rt < 4; rt++)
#pragma unroll
            for (int j = 0; j < 4; j++) {
                const int rl = wr * 64 + rt * 16 + hi * 4 + j;
                m[rt][j] = fmaxf(fmaxf(red[rl], red[128 + rl]),
                                 fmaxf(red[256 + rl], red[384 + rl]));
            }
        float ss[4][4];
#pragma unroll
        for (int rt = 0; rt < 4; rt++)
#pragma unroll
            for (int j = 0; j < 4; j++) ss[rt][j] = 0.f;
#pragma unroll
        for (int rt = 0; rt < 4; rt++)
#pragma unroll
            for (int ct = 0; ct < CT; ct++)
#pragma unroll
                for (int j = 0; j < 4; j++) {
                    const float e = __expf(acc[rt][ct][j] - m[rt][j]);
                    acc[rt][ct][j] = e;
                    ss[rt][j] += e;
                }
#pragma unroll
        for (int rt = 0; rt < 4; rt++)
#pragma unroll
            for (int j = 0; j < 4; j++) {
#pragma unroll
                for (int off = 1; off < 16; off <<= 1)
                    ss[rt][j] += __shfl_xor(ss[rt][j], off);
            }
        if (fr == 0) {
#pragma unroll
            for (int rt = 0; rt < 4; rt++)
#pragma unroll
                for (int j = 0; j < 4; j++)
                    red[512 + wc * 128 + wr * 64 + rt * 16 + hi * 4 + j] = ss[rt][j];
        }
        __syncthreads();
#pragma unroll
        for (int rt = 0; rt < 4; rt++)
#pragma unroll
            for (int j = 0; j < 4; j++) {
                const int rl = wr * 64 + rt * 16 + hi * 4 + j;
                m[rt][j] = 1.f / (red[512 + rl] + red[640 + rl] +
                                  red[768 + rl] + red[896 + rl]);
            }
        bf16* P = (bf16*)Cp;
#pragma unroll
        for (int rt = 0; rt < 4; rt++)
#pragma unroll
            for (int j = 0; j < 4; j++) {
                const int row = row0 + wr * 64 + rt * 16 + hi * 4 + j;
#pragma unroll
                for (int ct = 0; ct < CT; ct++) {
                    const int col = col0 + wc * CW + ct * 16 + fr;
                    P[cbase + (long)row * ldc + col] = (bf16)(acc[rt][ct][j] * m[rt][j]);
                }
            }
        return;
    }

#pragma unroll
    for (int rt = 0; rt < 4; rt++) {
#pragma unroll
        for (int j = 0; j < 4; j++) {
            const int row = row0 + wr * 64 + rt * 16 + hi * 4 + j;
#pragma unroll
            for (int ct = 0; ct < CT; ct++) {
                const int col = col0 + wc * CW + ct * 16 + fr;
                const float v = acc[rt][ct][j];
                const long idx = cbase + (long)row * ldc + col;
                if constexpr (EPI == 0) {
                    ((bf16*)Cp)[idx] = (bf16)v;
                } else {
                    ((float*)Cp)[idx] = v * scale;
                }
            }
        }
    }
}

// ---------------------------------------------------------------------------
// Split-K partial reduction: outb[i] = sum_p part[p*stride4 + i]  (float4)
// ---------------------------------------------------------------------------
__global__ void reduce_partials(const float* __restrict__ part,
                                float* __restrict__ outb,
                                long stride4, int P, int n4)
{
    const int i = blockIdx.x * 256 + threadIdx.x;
    if (i >= n4) return;
    float4 s = ((const float4*)part)[i];
    for (int p = 1; p < P; p++) {
        const float4 v = ((const float4*)part)[(long)p * stride4 + i];
        s.x += v.x; s.y += v.y; s.z += v.z; s.w += v.w;
    }
    ((float4*)outb)[i] = s;
}

// ---------------------------------------------------------------------------
// Elementwise f32 -> bf16 (4 per thread)
// ---------------------------------------------------------------------------
__global__ void cvt_f32_bf16(const float* __restrict__ in, bf16* __restrict__ out, int n4)
{
    const int i = blockIdx.x * 256 + threadIdx.x;
    if (i < n4) {
        const float4 v = *(const float4*)&in[(long)i * 4];
        union { bf16 h[4]; ushort4 u; } o;
        o.h[0] = (bf16)v.x; o.h[1] = (bf16)v.y; o.h[2] = (bf16)v.z; o.h[3] = (bf16)v.w;
        *(ushort4*)&out[(long)i * 4] = o.u;
    }
}

// ---------------------------------------------------------------------------
// Transpose + cvt for 512x512 fp32 weight matrices (W[c][j] -> Wt[j][c] bf16)
// ---------------------------------------------------------------------------
__global__ __launch_bounds__(256)
void wtrans(const float* __restrict__ Wq, const float* __restrict__ Wk,
            const float* __restrict__ Wv, const float* __restrict__ Wo,
            bf16* __restrict__ wqkv_t, bf16* __restrict__ wo_t)
{
    __shared__ __align__(16) float T[64][68];
    const int z = blockIdx.z;
    const float* src = (z == 0) ? Wq : (z == 1) ? Wk : (z == 2) ? Wv : Wo;
    bf16* dst = (z < 3) ? (wqkv_t + (long)z * 262144) : wo_t;
    const int r0 = blockIdx.x * 64, c0 = blockIdx.y * 64;
    const int t  = threadIdx.x;
    const int rl = t >> 2;
    const int cq = (t & 3) * 16;
#pragma unroll
    for (int i = 0; i < 4; i++) {
        const float4 v = *(const float4*)&src[(long)(r0 + rl) * 512 + c0 + cq + i * 4];
        T[cq + i * 4 + 0][rl] = v.x;
        T[cq + i * 4 + 1][rl] = v.y;
        T[cq + i * 4 + 2][rl] = v.z;
        T[cq + i * 4 + 3][rl] = v.w;
    }
    __syncthreads();
#pragma unroll
    for (int i = 0; i < 4; i++) {
        const float4 v = *(const float4*)&T[rl][cq + i * 4];
        union { bf16 h[4]; ushort4 u; } o;
        o.h[0] = (bf16)v.x; o.h[1] = (bf16)v.y; o.h[2] = (bf16)v.z; o.h[3] = (bf16)v.w;
        *(ushort4*)&dst[(long)(c0 + rl) * 512 + r0 + cq + i * 4] = o.u;
    }
}

// ---------------------------------------------------------------------------
// Transpose V region of qkv (bf16): vt[b*512 + (j-1024)][l] = qkv[b*256+l][j]
// ---------------------------------------------------------------------------
__global__ __launch_bounds__(256)
void vtrans(const bf16* __restrict__ qkv, bf16* __restrict__ vt)
{
    __shared__ __align__(16) bf16 T[64][72];
    const int t  = threadIdx.x;
    const int l0 = blockIdx.x * 64, j0 = blockIdx.y * 64, b = blockIdx.z;
    const int r  = t >> 3;
    const int c8 = (t & 7) * 8;
#pragma unroll
    for (int p = 0; p < 2; p++) {
        const int rr = r + p * 32;
        bf16 v[8];
        *(uint4*)v = *(const uint4*)&qkv[(long)(b * 256 + l0 + rr) * 1536 + 1024 + j0 + c8];
#pragma unroll
        for (int i = 0; i < 8; i++) T[c8 + i][rr] = v[i];
    }
    __syncthreads();
#pragma unroll
    for (int p = 0; p < 2; p++) {
        const int rr = r + p * 32;
        const uint4 val = *(const uint4*)&T[rr][c8];
        *(uint4*)&vt[(long)(b * 512 + j0 + rr) * 256 + l0 + c8] = val;
    }
}

// ---------------------------------------------------------------------------
// im2col scatter helper: pooled value (b,lp,c) -> 3 ic slots + boundary zeros
// ic layout: [32*Ld][1536], entry (l, ci*3+t) = pooled[l+t-1] (0 if OOB)
// ---------------------------------------------------------------------------
__device__ inline void ic_scatter(bf16* __restrict__ icb, int lp, int Ld, float pooled)
{
    const bf16 pb = (bf16)pooled;
    icb[(long)lp * 1536 + 1] = pb;
    if (lp + 1 < Ld) icb[(long)(lp + 1) * 1536] = pb;
    if (lp > 0)      icb[(long)(lp - 1) * 1536 + 2] = pb;
    if (lp == 0)      icb[0] = (bf16)0.f;
    if (lp == Ld - 1) icb[(long)(Ld - 1) * 1536 + 2] = (bf16)0.f;
}

// ---------------------------------------------------------------------------
// Head of cascade: attn_out = features + wo_p0 + wo_p1 (Wo split-K partials);
// writes out & sf, pool(k=2), im2col. One thread per pooled element.
// ---------------------------------------------------------------------------
__global__ void cascade_first(const float* __restrict__ features,
                              const float* __restrict__ p0,
                              const float* __restrict__ p1,
                              float* __restrict__ out,
                              float* __restrict__ sf,
                              bf16* __restrict__ ic)
{
    const int idx = blockIdx.x * 256 + threadIdx.x;
    const int c  = idx & 511;
    const int lp = (idx >> 9) & 127;
    const int b  = idx >> 16;
    const long e0 = (long)(b * 256 + lp * 2) * 512 + c;
    const long e1 = e0 + 512;
    const float a0 = features[e0] + p0[e0] + p1[e0];
    const float a1 = features[e1] + p0[e1] + p1[e1];
    out[e0] = a0; out[e1] = a1;
    sf[e0]  = a0; sf[e1]  = a1;
    ic_scatter(ic + (long)b * 128 * 1536 + (long)c * 3, lp, 128, (a0 + a1) * 0.5f);
}

// ---------------------------------------------------------------------------
// depth d>=1: upsample(conv_{d-1})+bias+relu -> sf writeback -> pool(k) ->
// im2col. One thread per pooled element (32*Ld*512).
// ---------------------------------------------------------------------------
__global__ void cascade_mid(const float* __restrict__ conv,
                            const float* __restrict__ bias_p,
                            float* __restrict__ sf,
                            bf16* __restrict__ ic,
                            int ldshift, int k, float invk, float scale)
{
    const int idx = blockIdx.x * 256 + threadIdx.x;
    const int Ld = 1 << ldshift;
    const int c  = idx & 511;
    const int lp = (idx >> 9) & (Ld - 1);
    const int b  = idx >> (9 + ldshift);
    const int Lprev = Ld << 1;
    const float bias = bias_p[c];
    float* sfp = sf + ((long)b * 256 + (long)lp * k) * 512 + c;
    const float* cvb = conv + (long)b * Lprev * 512 + c;
    float s = 0.f;
    for (int i = 0; i < k; i++) {
        const int j = lp * k + i;
        float coords = (j + 0.5f) * scale - 0.5f;
        coords = fminf(fmaxf(coords, 0.f), (float)(Lprev - 1));
        const int lo = (int)coords;
        const int hi2 = min(lo + 1, Lprev - 1);
        const float w = coords - (float)lo;
        const float vlo = fmaxf(cvb[(long)lo * 512] + bias, 0.f);
        const float vhi = fmaxf(cvb[(long)hi2 * 512] + bias, 0.f);
        const float v = sfp[(long)i * 512] + vlo * (1.f - w) + vhi * w;
        sfp[(long)i * 512] = v;
        s += v;
    }
    ic_scatter(ic + (long)b * Ld * 1536 + (long)c * 3, lp, Ld, s * invk);
}

// ---------------------------------------------------------------------------
// final: out = attn_out + sf + upsample(relu(conv5 + bias))
// ---------------------------------------------------------------------------
__global__ void upsample_final(const float* __restrict__ conv,
                               const float* __restrict__ bias_p,
                               const float* __restrict__ sf,
                               float* __restrict__ outp)
{
    const int idx = blockIdx.x * 256 + threadIdx.x;
    const int c = idx & 511;
    const int j = (idx >> 9) & 255;
    const int b = idx >> 17;
    const float bias = bias_p[c];
    float coords = (j + 0.5f) * (4.f / 256.f) - 0.5f;
    coords = fminf(fmaxf(coords, 0.f), 3.f);
    const int lo = (int)coords;
    const int hi2 = min(lo + 1, 3);
    const float w = coords - (float)lo;
    const long rb = (long)b * 4 * 512 + c;
    const float vlo = fmaxf(conv[rb + (long)lo * 512] + bias, 0.f);
    const float vhi = fmaxf(conv[rb + (long)hi2 * 512] + bias, 0.f);
    outp[idx] = outp[idx] + sf[idx] + vlo * (1.f - w) + vhi * w;
}

// ---------------------------------------------------------------------------
// workspace layout (bytes)
// ---------------------------------------------------------------------------
static const long OFF_XB    = 0;          //  8,388,608  features bf16
static const long OFF_WQKV  = 8388608;    //  1,572,864  [1536][512] bf16
static const long OFF_WO    = 9961472;    //    524,288  [512][512] bf16
static const long OFF_WCONV = 10485760;   //  9,437,184  [6][512][1536] bf16
static const long OFF_QKV   = 19922944;   // 25,165,824  [8192][1536] bf16
static const long OFF_VT    = 45088768;   //  8,388,608  [32][512][256] bf16
static const long OFF_P     = 53477376;   // 33,554,432  [65536][256] bf16
static const long OFF_CTX   = 87031808;   //  8,388,608  [8192][512] bf16
static const long OFF_WPART = 95420416;   // 33,554,432  [2][8192][512] f32 (Wo) then conv split-K partials
static const long OFF_IC    = 128974848;  // 12,582,912  [4096][1536] bf16
static const long OFF_CONVA = 141557760;  //  8,388,608  f32
static const long OFF_CONVB = 149946368;  //  4,194,304  f32
static const long OFF_SF    = 154140672;  // 16,777,216  [8192][512] f32
// total: 170,917,888 bytes

extern "C" void kernel_launch(void* const* d_in, const int* in_sizes, int n_in,
                              void* d_out, int out_size, void* d_ws, size_t ws_size,
                              hipStream_t stream)
{
    const float* features = (const float*)d_in[0];
    const float* Wq = (const float*)d_in[1];
    const float* Wk = (const float*)d_in[2];
    const float* Wv = (const float*)d_in[3];
    const float* Wo = (const float*)d_in[4];
    const float* conv_w = (const float*)d_in[5];
    const float* conv_b = (const float*)d_in[6];
    float* out = (float*)d_out;

    char* ws = (char*)d_ws;
    bf16* xb     = (bf16*)(ws + OFF_XB);
    bf16* wqkv_t = (bf16*)(ws + OFF_WQKV);
    bf16* wo_t   = (bf16*)(ws + OFF_WO);
    bf16* wconv  = (bf16*)(ws + OFF_WCONV);
    bf16* qkv    = (bf16*)(ws + OFF_QKV);
    bf16* vt     = (bf16*)(ws + OFF_VT);
    bf16* P      = (bf16*)(ws + OFF_P);
    bf16* ctx    = (bf16*)(ws + OFF_CTX);
    float* wpart = (float*)(ws + OFF_WPART);
    bf16* ic     = (bf16*)(ws + OFF_IC);
    float* convA = (float*)(ws + OFF_CONVA);
    float* convB = (float*)(ws + OFF_CONVB);
    float* sf    = (float*)(ws + OFF_SF);
    float* convbuf[2] = {convA, convB};

    // --- input conversions ---
    cvt_f32_bf16<<<4096, 256, 0, stream>>>(features, xb, 1048576);
    cvt_f32_bf16<<<4608, 256, 0, stream>>>(conv_w, wconv, 1179648);
    wtrans<<<dim3(8, 8, 4), 256, 0, stream>>>(Wq, Wk, Wv, Wo, wqkv_t, wo_t);

    // --- fused QKV projection: qkv[8192][1536] ---
    gemm_bt<0, 128><<<dim3(768, 1, 1), 512, 0, stream>>>(
        xb, 512, 0, 0, wqkv_t, 512, 0, 0, qkv, 1536, 0, 0, 0,
        512, 12, 1.f);

    // --- V transpose for PV GEMM ---
    vtrans<<<dim3(4, 8, 32), 256, 0, stream>>>(qkv, vt);

    // --- scores + fused softmax -> P bf16, batched over 256 (b,h) ---
    gemm_bt<4, 256><<<dim3(2, 256, 1), 512, 0, stream>>>(
        qkv, 1536, 393216, 64,
        qkv + 512, 1536, 393216, 64,
        P, 256, 524288, 65536, 0,
        64, 1, 0.125f);

    // --- ctx = P @ V : Bt = V^T (vt) ---
    gemm_bt<0, 64><<<dim3(2, 256, 1), 512, 0, stream>>>(
        P, 256, 524288, 65536,
        vt, 256, 131072, 16384,
        ctx, 512, 131072, 64, 0,
        256, 1, 1.f);

    // --- Wo GEMM, split-K=2 into partial buffers ---
    gemm_bt<1, 128><<<dim3(256, 1, 2), 512, 0, stream>>>(
        ctx, 512, 0, 0, wo_t, 512, 0, 0,
        wpart, 512, 0, 0, 4194304,
        256, 4, 1.f);

    // --- ScaleFeatures cascade (split-K partials + reduce, no atomics) ---
    static const int SPL[6] = {4, 8, 16, 16, 16, 16};

    // d = 0 (also materializes attn_out into out & sf)
    cascade_first<<<8192, 256, 0, stream>>>(
        features, wpart, wpart + 4194304, out, sf, ic);
    {
        const int M = 4096;
        gemm_bt<1, 128><<<dim3(128, 1, SPL[0]), 512, 0, stream>>>(
            ic, 1536, 0, 0, wconv, 1536, 0, 0,
            wpart, 512, 0, 0, (long)M * 512,
            1536 / SPL[0], 4, 1.f);
        reduce_partials<<<(M * 128) / 256, 256, 0, stream>>>(
            wpart, convbuf[0], (long)M * 128, SPL[0], M * 128);
    }

    // d = 1..5
    for (int d = 1; d < 6; d++) {
        const int ldshift = 7 - d;
        const int Ld = 1 << ldshift;
        const int k  = 2 << d;
        const int M  = 32 * Ld;
        cascade_mid<<<64 * Ld, 256, 0, stream>>>(
            convbuf[(d - 1) & 1], conv_b + (d - 1) * 512, sf, ic,
            ldshift, k, 1.0f / (float)k, (float)(2 * Ld) / 256.f);
        gemm_bt<1, 128><<<dim3((M / 128) * 4, 1, SPL[d]), 512, 0, stream>>>(
            ic, 1536, 0, 0,
            wconv + (long)d * 786432, 1536, 0, 0,
            wpart, 512, 0, 0, (long)M * 512,
            1536 / SPL[d], 4, 1.f);
        reduce_partials<<<(M * 128) / 256, 256, 0, stream>>>(
            wpart, convbuf[d & 1], (long)M * 128, SPL[d], M * 128);
    }

    // --- final: out = attn_out + sf + up(relu(conv5 + b5)) ---
    upsample_final<<<16384, 256, 0, stream>>>(
        convbuf[1], conv_b + 5 * 512, sf, out);
}

// Round 13
// 361.514 us; speedup vs baseline: 1.1214x; 1.0191x over previous
//
#include <hip/hip_runtime.h>
#include <hip/hip_bf16.h>

typedef __bf16 bf16;
typedef __attribute__((ext_vector_type(8))) __bf16 bf16x8;
typedef __attribute__((ext_vector_type(4))) float f32x4;

#define GLDS16(gp, lp) __builtin_amdgcn_global_load_lds( \
    (const __attribute__((address_space(1))) void*)(gp),  \
    (__attribute__((address_space(3))) void*)(lp), 16, 0, 0)

// ---------------------------------------------------------------------------
// Generic bf16 MFMA GEMM:  C[i][j] = sum_k A[i][k] * Bt[j][k]   (Bt = B^T)
// Tile 128 x BN, BK=32, 512 threads = 8 waves (2x4). Double-buffered LDS,
// 2-phase pipeline. blockIdx.y = batch; blockIdx.z = K-split (chunk KC,
// output offset z*zC -> partial buffers, NO atomics).
// EPI: 0 = store bf16; 1 = store f32*scale (+z*zC partial offset).
// ---------------------------------------------------------------------------
template<int EPI, int BN>
__global__ __launch_bounds__(512)
void gemm_bt(const bf16* __restrict__ A, int lda, long sAb, long sAh,
             const bf16* __restrict__ Bt, int ldb, long sBb, long sBh,
             void* __restrict__ Cp, int ldc, long sCb, long sCh, long zC,
             int KC, int tilesN, float scale)
{
    constexpr int CT = BN / 64;      // col frags per wave
    constexpr int CW = 16 * CT;      // cols per wave

    __shared__ __align__(16) bf16 Al[2][128 * 32];
    __shared__ __align__(16) bf16 Bl[2][BN * 32];

    const int t    = threadIdx.x;
    const int lane = t & 63;
    const int w    = t >> 6;
    const int wr   = w >> 2, wc = w & 3;
    const int tm = blockIdx.x / tilesN, tn = blockIdx.x % tilesN;
    const int row0 = tm * 128, col0 = tn * BN;
    const int bb = blockIdx.y >> 3, bh = blockIdx.y & 7;
    const int koff = blockIdx.z * KC;

    const bf16* Ab = A  + (long)bb * sAb + (long)bh * sAh;
    const bf16* Bb = Bt + (long)bb * sBb + (long)bh * sBh;

    const int sr = t >> 2;
    const int sc = (t & 3) * 8;
    const long aoff  = (long)(row0 + sr) * lda + koff + sc;
    const long boff0 = (long)(col0 + sr) * ldb + koff + sc;
    const long boff1 = (long)(col0 + 128 + sr) * ldb + koff + sc;  // BN==256 only

    f32x4 acc[4][CT];
#pragma unroll
    for (int i = 0; i < 4; i++)
#pragma unroll
        for (int j = 0; j < CT; j++) acc[i][j] = (f32x4){0.f, 0.f, 0.f, 0.f};

    const int fr = lane & 15, hi = lane >> 4;
    const int nt = KC >> 5;
    int cur = 0;

    auto STAGE = [&](int buf, int kk) {
        GLDS16(Ab + aoff + kk, &Al[buf][w * 512]);
        if constexpr (BN >= 128) {
            GLDS16(Bb + boff0 + kk, &Bl[buf][w * 512]);
            if constexpr (BN == 256)
                GLDS16(Bb + boff1 + kk, &Bl[buf][4096 + w * 512]);
        } else {
            if (w < 4) GLDS16(Bb + boff0 + kk, &Bl[buf][w * 512]);
        }
    };

    STAGE(0, 0);
    __syncthreads();

    for (int tt = 0; tt < nt; ++tt) {
        if (tt + 1 < nt) STAGE(cur ^ 1, (tt + 1) * 32);
        bf16x8 af[4], bfr[CT];
#pragma unroll
        for (int rt = 0; rt < 4; rt++)
            af[rt] = *(const bf16x8*)&Al[cur][(wr * 64 + rt * 16 + fr) * 32 + hi * 8];
#pragma unroll
        for (int ct = 0; ct < CT; ct++)
            bfr[ct] = *(const bf16x8*)&Bl[cur][(wc * CW + ct * 16 + fr) * 32 + hi * 8];
#pragma unroll
        for (int rt = 0; rt < 4; rt++)
#pragma unroll
            for (int ct = 0; ct < CT; ct++)
                acc[rt][ct] = __builtin_amdgcn_mfma_f32_16x16x32_bf16(
                    af[rt], bfr[ct], acc[rt][ct], 0, 0, 0);
        __syncthreads();   // drains vmcnt(0)+lgkmcnt(0): stage(t+1) complete
        cur ^= 1;
    }

    const long cbase = (long)bb * sCb + (long)bh * sCh + (long)blockIdx.z * zC;

#pragma unroll
    for (int rt = 0; rt < 4; rt++) {
#pragma unroll
        for (int j = 0; j < 4; j++) {
            const int row = row0 + wr * 64 + rt * 16 + hi * 4 + j;
#pragma unroll
            for (int ct = 0; ct < CT; ct++) {
                const int col = col0 + wc * CW + ct * 16 + fr;
                const float v = acc[rt][ct][j];
                const long idx = cbase + (long)row * ldc + col;
                if constexpr (EPI == 0) {
                    ((bf16*)Cp)[idx] = (bf16)v;
                } else {
                    ((float*)Cp)[idx] = v * scale;
                }
            }
        }
    }
}

// ---------------------------------------------------------------------------
// Fused attention for one (b,h), 128 q-rows per block, full 256 keys.
// grid (2, 256), 512 threads = 8 waves.
//   phase 0: V -> regs (issued early, latency hides under QK^T)
//   phase 1: S = Q@K^T from GLOBAL (qkv is L2/L3-hot; K=64 -> 2 MFMA steps)
//   phase 2: V regs -> LDS transposed Vt[64][264]
//   phase 3: row softmax (identical structure to old EPI=4 epilogue)
//   phase 4: P -> LDS Pl[128][264] bf16
//   phase 5: ctx = P@V from LDS (8 K-steps), store bf16
// LDS = 67584 (Pl) + 33792 (Vt) + 4096 (red) = 105472 B -> 1 block/CU.
// ---------------------------------------------------------------------------
__global__ __launch_bounds__(512)
void attn_fused(const bf16* __restrict__ qkv, bf16* __restrict__ ctx)
{
    __shared__ __align__(16) char smem[105472];
    bf16*  Pl  = (bf16*)smem;                   // [128][264]
    bf16*  Vt  = (bf16*)(smem + 67584);         // [64][264]
    float* red = (float*)(smem + 101376);       // [1024]

    const int t    = threadIdx.x;
    const int lane = t & 63;
    const int w    = t >> 6;
    const int wr   = w >> 2, wc = w & 3;        // 2 x 4 waves
    const int fr = lane & 15, hi = lane >> 4;
    const int row0 = blockIdx.x * 128;
    const int b = blockIdx.y >> 3, h = blockIdx.y & 7;

    const bf16* qbase = qkv + (long)b * 393216 + h * 64;
    const bf16* kbase = qbase + 512;
    const bf16* vbase = qbase + 1024;

    // ---- phase 0: V tile -> registers (scatter-write to Vt later) ----
    bf16x8 vreg[4];
#pragma unroll
    for (int p = 0; p < 4; p++) {
        const int q = p * 512 + t;
        const int m  = q >> 3;
        const int c8 = (q & 7) * 8;
        vreg[p] = *(const bf16x8*)(vbase + (long)m * 1536 + c8);
    }

    // ---- phase 1: QK^T from global ----
    f32x4 acc[4][4];
#pragma unroll
    for (int i = 0; i < 4; i++)
#pragma unroll
        for (int j = 0; j < 4; j++) acc[i][j] = (f32x4){0.f, 0.f, 0.f, 0.f};

#pragma unroll
    for (int kc = 0; kc < 2; kc++) {
        bf16x8 af[4], bfr[4];
#pragma unroll
        for (int rt = 0; rt < 4; rt++) {
            const int l = row0 + wr * 64 + rt * 16 + fr;
            af[rt] = *(const bf16x8*)(qbase + (long)l * 1536 + kc * 32 + hi * 8);
        }
#pragma unroll
        for (int ct = 0; ct < 4; ct++) {
            const int m = wc * 64 + ct * 16 + fr;
            bfr[ct] = *(const bf16x8*)(kbase + (long)m * 1536 + kc * 32 + hi * 8);
        }
#pragma unroll
        for (int rt = 0; rt < 4; rt++)
#pragma unroll
            for (int ct = 0; ct < 4; ct++)
                acc[rt][ct] = __builtin_amdgcn_mfma_f32_16x16x32_bf16(
                    af[rt], bfr[ct], acc[rt][ct], 0, 0, 0);
    }

    // ---- phase 2: write V transposed into LDS ----
#pragma unroll
    for (int p = 0; p < 4; p++) {
        const int q = p * 512 + t;
        const int m  = q >> 3;
        const int c8 = (q & 7) * 8;
#pragma unroll
        for (int i = 0; i < 8; i++)
            Vt[(c8 + i) * 264 + m] = vreg[p][i];
    }

    // ---- phase 3: row softmax over 256 cols (scale 1/8) ----
#pragma unroll
    for (int rt = 0; rt < 4; rt++)
#pragma unroll
        for (int ct = 0; ct < 4; ct++) acc[rt][ct] *= 0.125f;

    float m4[4][4];
#pragma unroll
    for (int rt = 0; rt < 4; rt++)
#pragma unroll
        for (int j = 0; j < 4; j++) {
            float mm = acc[rt][0][j];
#pragma unroll
            for (int ct = 1; ct < 4; ct++) mm = fmaxf(mm, acc[rt][ct][j]);
#pragma unroll
            for (int off = 1; off < 16; off <<= 1)
                mm = fmaxf(mm, __shfl_xor(mm, off));
            m4[rt][j] = mm;
        }
    if (fr == 0) {
#pragma unroll
        for (int rt = 0; rt < 4; rt++)
#pragma unroll
            for (int j = 0; j < 4; j++)
                red[wc * 128 + wr * 64 + rt * 16 + hi * 4 + j] = m4[rt][j];
    }
    __syncthreads();   // red ready; also: all vreg->Vt writes ordered before later reads
#pragma unroll
    for (int rt = 0; rt < 4; rt++)
#pragma unroll
        for (int j = 0; j < 4; j++) {
            const int rl = wr * 64 + rt * 16 + hi * 4 + j;
            m4[rt][j] = fmaxf(fmaxf(red[rl], red[128 + rl]),
                              fmaxf(red[256 + rl], red[384 + rl]));
        }
    float ss[4][4];
#pragma unroll
    for (int rt = 0; rt < 4; rt++)
#pragma unroll
        for (int j = 0; j < 4; j++) ss[rt][j] = 0.f;
#pragma unroll
    for (int rt = 0; rt < 4; rt++)
#pragma unroll
        for (int ct = 0; ct < 4; ct++)
#pragma unroll
            for (int j = 0; j < 4; j++) {
                const float e = __expf(acc[rt][ct][j] - m4[rt][j]);
                acc[rt][ct][j] = e;
                ss[rt][j] += e;
            }
#pragma unroll
    for (int rt = 0; rt < 4; rt++)
#pragma unroll
        for (int j = 0; j < 4; j++) {
#pragma unroll
            for (int off = 1; off < 16; off <<= 1)
                ss[rt][j] += __shfl_xor(ss[rt][j], off);
        }
    if (fr == 0) {
#pragma unroll
        for (int rt = 0; rt < 4; rt++)
#pragma unroll
            for (int j = 0; j < 4; j++)
                red[512 + wc * 128 + wr * 64 + rt * 16 + hi * 4 + j] = ss[rt][j];
    }
    __syncthreads();
#pragma unroll
    for (int rt = 0; rt < 4; rt++)
#pragma unroll
        for (int j = 0; j < 4; j++) {
            const int rl = wr * 64 + rt * 16 + hi * 4 + j;
            m4[rt][j] = 1.f / (red[512 + rl] + red[640 + rl] +
                               red[768 + rl] + red[896 + rl]);
        }

    // ---- phase 4: P -> LDS bf16 ----
#pragma unroll
    for (int rt = 0; rt < 4; rt++)
#pragma unroll
        for (int j = 0; j < 4; j++) {
            const int rl = wr * 64 + rt * 16 + hi * 4 + j;
#pragma unroll
            for (int ct = 0; ct < 4; ct++) {
                const int col = wc * 64 + ct * 16 + fr;
                Pl[rl * 264 + col] = (bf16)(acc[rt][ct][j] * m4[rt][j]);
            }
        }
    __syncthreads();   // Pl + Vt ready

    // ---- phase 5: ctx = P @ V  (output 128 x 64; per wave 64 rows x 16 cols) ----
    f32x4 acc2[4];
#pragma unroll
    for (int i = 0; i < 4; i++) acc2[i] = (f32x4){0.f, 0.f, 0.f, 0.f};

#pragma unroll
    for (int ks = 0; ks < 8; ks++) {
        const int k0 = ks * 32;
        bf16x8 af2[4], bfr2;
#pragma unroll
        for (int rt = 0; rt < 4; rt++)
            af2[rt] = *(const bf16x8*)&Pl[(wr * 64 + rt * 16 + fr) * 264 + k0 + hi * 8];
        bfr2 = *(const bf16x8*)&Vt[(wc * 16 + fr) * 264 + k0 + hi * 8];
#pragma unroll
        for (int rt = 0; rt < 4; rt++)
            acc2[rt] = __builtin_amdgcn_mfma_f32_16x16x32_bf16(
                af2[rt], bfr2, acc2[rt], 0, 0, 0);
    }

#pragma unroll
    for (int rt = 0; rt < 4; rt++)
#pragma unroll
        for (int j = 0; j < 4; j++) {
            const int l = row0 + wr * 64 + rt * 16 + hi * 4 + j;
            const int d = wc * 16 + fr;
            ctx[(long)(b * 256 + l) * 512 + h * 64 + d] = (bf16)(acc2[rt][j]);
        }
}

// ---------------------------------------------------------------------------
// Split-K partial reduction: outb[i] = sum_p part[p*stride4 + i]  (float4)
// ---------------------------------------------------------------------------
__global__ void reduce_partials(const float* __restrict__ part,
                                float* __restrict__ outb,
                                long stride4, int P, int n4)
{
    const int i = blockIdx.x * 256 + threadIdx.x;
    if (i >= n4) return;
    float4 s = ((const float4*)part)[i];
    for (int p = 1; p < P; p++) {
        const float4 v = ((const float4*)part)[(long)p * stride4 + i];
        s.x += v.x; s.y += v.y; s.z += v.z; s.w += v.w;
    }
    ((float4*)outb)[i] = s;
}

// ---------------------------------------------------------------------------
// Elementwise f32 -> bf16 (4 per thread)
// ---------------------------------------------------------------------------
__global__ void cvt_f32_bf16(const float* __restrict__ in, bf16* __restrict__ out, int n4)
{
    const int i = blockIdx.x * 256 + threadIdx.x;
    if (i < n4) {
        const float4 v = *(const float4*)&in[(long)i * 4];
        union { bf16 h[4]; ushort4 u; } o;
        o.h[0] = (bf16)v.x; o.h[1] = (bf16)v.y; o.h[2] = (bf16)v.z; o.h[3] = (bf16)v.w;
        *(ushort4*)&out[(long)i * 4] = o.u;
    }
}

// ---------------------------------------------------------------------------
// Transpose + cvt for 512x512 fp32 weight matrices (W[c][j] -> Wt[j][c] bf16)
// ---------------------------------------------------------------------------
__global__ __launch_bounds__(256)
void wtrans(const float* __restrict__ Wq, const float* __restrict__ Wk,
            const float* __restrict__ Wv, const float* __restrict__ Wo,
            bf16* __restrict__ wqkv_t, bf16* __restrict__ wo_t)
{
    __shared__ __align__(16) float T[64][68];
    const int z = blockIdx.z;
    const float* src = (z == 0) ? Wq : (z == 1) ? Wk : (z == 2) ? Wv : Wo;
    bf16* dst = (z < 3) ? (wqkv_t + (long)z * 262144) : wo_t;
    const int r0 = blockIdx.x * 64, c0 = blockIdx.y * 64;
    const int t  = threadIdx.x;
    const int rl = t >> 2;
    const int cq = (t & 3) * 16;
#pragma unroll
    for (int i = 0; i < 4; i++) {
        const float4 v = *(const float4*)&src[(long)(r0 + rl) * 512 + c0 + cq + i * 4];
        T[cq + i * 4 + 0][rl] = v.x;
        T[cq + i * 4 + 1][rl] = v.y;
        T[cq + i * 4 + 2][rl] = v.z;
        T[cq + i * 4 + 3][rl] = v.w;
    }
    __syncthreads();
#pragma unroll
    for (int i = 0; i < 4; i++) {
        const float4 v = *(const float4*)&T[rl][cq + i * 4];
        union { bf16 h[4]; ushort4 u; } o;
        o.h[0] = (bf16)v.x; o.h[1] = (bf16)v.y; o.h[2] = (bf16)v.z; o.h[3] = (bf16)v.w;
        *(ushort4*)&dst[(long)(c0 + rl) * 512 + r0 + cq + i * 4] = o.u;
    }
}

// ---------------------------------------------------------------------------
// im2col scatter helper: pooled value (b,lp,c) -> 3 ic slots + boundary zeros
// ---------------------------------------------------------------------------
__device__ inline void ic_scatter(bf16* __restrict__ icb, int lp, int Ld, float pooled)
{
    const bf16 pb = (bf16)pooled;
    icb[(long)lp * 1536 + 1] = pb;
    if (lp + 1 < Ld) icb[(long)(lp + 1) * 1536] = pb;
    if (lp > 0)      icb[(long)(lp - 1) * 1536 + 2] = pb;
    if (lp == 0)      icb[0] = (bf16)0.f;
    if (lp == Ld - 1) icb[(long)(Ld - 1) * 1536 + 2] = (bf16)0.f;
}

// ---------------------------------------------------------------------------
// Head of cascade: attn_out = features + wo_p0 + wo_p1 (Wo split-K partials);
// writes out & sf, pool(k=2), im2col. One thread per pooled element.
// ---------------------------------------------------------------------------
__global__ void cascade_first(const float* __restrict__ features,
                              const float* __restrict__ p0,
                              const float* __restrict__ p1,
                              float* __restrict__ out,
                              float* __restrict__ sf,
                              bf16* __restrict__ ic)
{
    const int idx = blockIdx.x * 256 + threadIdx.x;
    const int c  = idx & 511;
    const int lp = (idx >> 9) & 127;
    const int b  = idx >> 16;
    const long e0 = (long)(b * 256 + lp * 2) * 512 + c;
    const long e1 = e0 + 512;
    const float a0 = features[e0] + p0[e0] + p1[e0];
    const float a1 = features[e1] + p0[e1] + p1[e1];
    out[e0] = a0; out[e1] = a1;
    sf[e0]  = a0; sf[e1]  = a1;
    ic_scatter(ic + (long)b * 128 * 1536 + (long)c * 3, lp, 128, (a0 + a1) * 0.5f);
}

// ---------------------------------------------------------------------------
// depth d>=1: upsample(conv_{d-1})+bias+relu -> sf writeback -> pool(k) ->
// im2col. One thread per pooled element (32*Ld*512).
// ---------------------------------------------------------------------------
__global__ void cascade_mid(const float* __restrict__ conv,
                            const float* __restrict__ bias_p,
                            float* __restrict__ sf,
                            bf16* __restrict__ ic,
                            int ldshift, int k, float invk, float scale)
{
    const int idx = blockIdx.x * 256 + threadIdx.x;
    const int Ld = 1 << ldshift;
    const int c  = idx & 511;
    const int lp = (idx >> 9) & (Ld - 1);
    const int b  = idx >> (9 + ldshift);
    const int Lprev = Ld << 1;
    const float bias = bias_p[c];
    float* sfp = sf + ((long)b * 256 + (long)lp * k) * 512 + c;
    const float* cvb = conv + (long)b * Lprev * 512 + c;
    float s = 0.f;
    for (int i = 0; i < k; i++) {
        const int j = lp * k + i;
        float coords = (j + 0.5f) * scale - 0.5f;
        coords = fminf(fmaxf(coords, 0.f), (float)(Lprev - 1));
        const int lo = (int)coords;
        const int hi2 = min(lo + 1, Lprev - 1);
        const float w = coords - (float)lo;
        const float vlo = fmaxf(cvb[(long)lo * 512] + bias, 0.f);
        const float vhi = fmaxf(cvb[(long)hi2 * 512] + bias, 0.f);
        const float v = sfp[(long)i * 512] + vlo * (1.f - w) + vhi * w;
        sfp[(long)i * 512] = v;
        s += v;
    }
    ic_scatter(ic + (long)b * Ld * 1536 + (long)c * 3, lp, Ld, s * invk);
}

// ---------------------------------------------------------------------------
// final: out = attn_out + sf + upsample(relu(conv5 + bias))
// ---------------------------------------------------------------------------
__global__ void upsample_final(const float* __restrict__ conv,
                               const float* __restrict__ bias_p,
                               const float* __restrict__ sf,
                               float* __restrict__ outp)
{
    const int idx = blockIdx.x * 256 + threadIdx.x;
    const int c = idx & 511;
    const int j = (idx >> 9) & 255;
    const int b = idx >> 17;
    const float bias = bias_p[c];
    float coords = (j + 0.5f) * (4.f / 256.f) - 0.5f;
    coords = fminf(fmaxf(coords, 0.f), 3.f);
    const int lo = (int)coords;
    const int hi2 = min(lo + 1, 3);
    const float w = coords - (float)lo;
    const long rb = (long)b * 4 * 512 + c;
    const float vlo = fmaxf(conv[rb + (long)lo * 512] + bias, 0.f);
    const float vhi = fmaxf(conv[rb + (long)hi2 * 512] + bias, 0.f);
    outp[idx] = outp[idx] + sf[idx] + vlo * (1.f - w) + vhi * w;
}

// ---------------------------------------------------------------------------
// workspace layout (bytes)
// ---------------------------------------------------------------------------
static const long OFF_XB    = 0;          //  8,388,608  features bf16
static const long OFF_WQKV  = 8388608;    //  1,572,864  [1536][512] bf16
static const long OFF_WO    = 9961472;    //    524,288  [512][512] bf16
static const long OFF_WCONV = 10485760;   //  9,437,184  [6][512][1536] bf16
static const long OFF_QKV   = 19922944;   // 25,165,824  [8192][1536] bf16
static const long OFF_CTX   = 87031808;   //  8,388,608  [8192][512] bf16
static const long OFF_WPART = 95420416;   // 33,554,432  [2][8192][512] f32 (Wo) then conv split-K partials
static const long OFF_IC    = 128974848;  // 12,582,912  [4096][1536] bf16
static const long OFF_CONVA = 141557760;  //  8,388,608  f32
static const long OFF_CONVB = 149946368;  //  4,194,304  f32
static const long OFF_SF    = 154140672;  // 16,777,216  [8192][512] f32
// total: 170,917,888 bytes

extern "C" void kernel_launch(void* const* d_in, const int* in_sizes, int n_in,
                              void* d_out, int out_size, void* d_ws, size_t ws_size,
                              hipStream_t stream)
{
    const float* features = (const float*)d_in[0];
    const float* Wq = (const float*)d_in[1];
    const float* Wk = (const float*)d_in[2];
    const float* Wv = (const float*)d_in[3];
    const float* Wo = (const float*)d_in[4];
    const float* conv_w = (const float*)d_in[5];
    const float* conv_b = (const float*)d_in[6];
    float* out = (float*)d_out;

    char* ws = (char*)d_ws;
    bf16* xb     = (bf16*)(ws + OFF_XB);
    bf16* wqkv_t = (bf16*)(ws + OFF_WQKV);
    bf16* wo_t   = (bf16*)(ws + OFF_WO);
    bf16* wconv  = (bf16*)(ws + OFF_WCONV);
    bf16* qkv    = (bf16*)(ws + OFF_QKV);
    bf16* ctx    = (bf16*)(ws + OFF_CTX);
    float* wpart = (float*)(ws + OFF_WPART);
    bf16* ic     = (bf16*)(ws + OFF_IC);
    float* convA = (float*)(ws + OFF_CONVA);
    float* convB = (float*)(ws + OFF_CONVB);
    float* sf    = (float*)(ws + OFF_SF);
    float* convbuf[2] = {convA, convB};

    // --- input conversions ---
    cvt_f32_bf16<<<4096, 256, 0, stream>>>(features, xb, 1048576);
    cvt_f32_bf16<<<4608, 256, 0, stream>>>(conv_w, wconv, 1179648);
    wtrans<<<dim3(8, 8, 4), 256, 0, stream>>>(Wq, Wk, Wv, Wo, wqkv_t, wo_t);

    // --- fused QKV projection: qkv[8192][1536] ---
    gemm_bt<0, 128><<<dim3(768, 1, 1), 512, 0, stream>>>(
        xb, 512, 0, 0, wqkv_t, 512, 0, 0, qkv, 1536, 0, 0, 0,
        512, 12, 1.f);

    // --- fused attention: qkv -> ctx (one kernel; P never leaves the CU) ---
    attn_fused<<<dim3(2, 256), 512, 0, stream>>>(qkv, ctx);

    // --- Wo GEMM, split-K=2 into partial buffers ---
    gemm_bt<1, 128><<<dim3(256, 1, 2), 512, 0, stream>>>(
        ctx, 512, 0, 0, wo_t, 512, 0, 0,
        wpart, 512, 0, 0, 4194304,
        256, 4, 1.f);

    // --- ScaleFeatures cascade (split-K partials + reduce, no atomics) ---
    static const int SPL[6] = {4, 8, 16, 16, 16, 16};

    // d = 0 (also materializes attn_out into out & sf)
    cascade_first<<<8192, 256, 0, stream>>>(
        features, wpart, wpart + 4194304, out, sf, ic);
    {
        const int M = 4096;
        gemm_bt<1, 128><<<dim3(128, 1, SPL[0]), 512, 0, stream>>>(
            ic, 1536, 0, 0, wconv, 1536, 0, 0,
            wpart, 512, 0, 0, (long)M * 512,
            1536 / SPL[0], 4, 1.f);
        reduce_partials<<<(M * 128) / 256, 256, 0, stream>>>(
            wpart, convbuf[0], (long)M * 128, SPL[0], M * 128);
    }

    // d = 1..5
    for (int d = 1; d < 6; d++) {
        const int ldshift = 7 - d;
        const int Ld = 1 << ldshift;
        const int k  = 2 << d;
        const int M  = 32 * Ld;
        cascade_mid<<<64 * Ld, 256, 0, stream>>>(
            convbuf[(d - 1) & 1], conv_b + (d - 1) * 512, sf, ic,
            ldshift, k, 1.0f / (float)k, (float)(2 * Ld) / 256.f);
        gemm_bt<1, 128><<<dim3((M / 128) * 4, 1, SPL[d]), 512, 0, stream>>>(
            ic, 1536, 0, 0,
            wconv + (long)d * 786432, 1536, 0, 0,
            wpart, 512, 0, 0, (long)M * 512,
            1536 / SPL[d], 4, 1.f);
        reduce_partials<<<(M * 128) / 256, 256, 0, stream>>>(
            wpart, convbuf[d & 1], (long)M * 128, SPL[d], M * 128);
    }

    // --- final: out = attn_out + sf + up(relu(conv5 + b5)) ---
    upsample_final<<<16384, 256, 0, stream>>>(
        convbuf[1], conv_b + 5 * 512, sf, out);
}